// Round 1
// baseline (108.782 us; speedup 1.0000x reference)
//
#include <hip/hip_runtime.h>

// out[b,k,h,w] = w[k,0]*side5 + w[k,1]*side4 + w[k,2]*side1 + w[k,3]*side2
//              + w[k,4]*side3 + bias[k]
// B=8, K=19, H=W=512. Fixed-size problem -> bake the constants.

#define KK   19
#define HW4  65536      // (512*512)/4 float4s per plane
#define N4   (8 * KK * HW4)

__global__ __launch_bounds__(256) void grouped_conv_fuse_kernel(
    const float* __restrict__ s1, const float* __restrict__ s2,
    const float* __restrict__ s3, const float* __restrict__ s4,
    const float* __restrict__ s5, const float* __restrict__ w,
    const float* __restrict__ bias, float* __restrict__ out)
{
    const float4* __restrict__ v1 = (const float4*)s1;
    const float4* __restrict__ v2 = (const float4*)s2;
    const float4* __restrict__ v3 = (const float4*)s3;
    const float4* __restrict__ v4 = (const float4*)s4;
    const float4* __restrict__ v5 = (const float4*)s5;
    float4* __restrict__ vo = (float4*)out;

    int idx    = blockIdx.x * 256 + threadIdx.x;
    int stride = gridDim.x * 256;

    for (int i = idx; i < N4; i += stride) {
        int kb = i >> 16;          // b*K + k   (HW4 = 2^16)
        int sp = i & (HW4 - 1);    // spatial float4 index
        int b  = kb / KK;          // kb < 152, cheap const div
        int k  = kb - b * KK;
        int si = (b << 16) + sp;

        float4 x5 = v5[i];
        float4 x4 = v4[i];
        float4 a1 = v1[si];
        float4 a2 = v2[si];
        float4 a3 = v3[si];

        // wave-uniform (all lanes share k) -> scalar loads
        float w0 = w[k * 5 + 0];
        float w1 = w[k * 5 + 1];
        float w2 = w[k * 5 + 2];
        float w3 = w[k * 5 + 3];
        float w4 = w[k * 5 + 4];
        float bb = bias[k];

        float4 o;
        o.x = w0 * x5.x + w1 * x4.x + w2 * a1.x + w3 * a2.x + w4 * a3.x + bb;
        o.y = w0 * x5.y + w1 * x4.y + w2 * a1.y + w3 * a2.y + w4 * a3.y + bb;
        o.z = w0 * x5.z + w1 * x4.z + w2 * a1.z + w3 * a2.z + w4 * a3.z + bb;
        o.w = w0 * x5.w + w1 * x4.w + w2 * a1.w + w3 * a2.w + w4 * a3.w + bb;
        vo[i] = o;
    }
}

extern "C" void kernel_launch(void* const* d_in, const int* in_sizes, int n_in,
                              void* d_out, int out_size, void* d_ws, size_t ws_size,
                              hipStream_t stream) {
    const float* s1   = (const float*)d_in[0];
    const float* s2   = (const float*)d_in[1];
    const float* s3   = (const float*)d_in[2];
    const float* s4   = (const float*)d_in[3];
    const float* s5   = (const float*)d_in[4];
    const float* w    = (const float*)d_in[5];
    const float* bias = (const float*)d_in[6];
    float* out        = (float*)d_out;

    int total_blocks = N4 / 256;            // 38912
    int grid = total_blocks < 2048 ? total_blocks : 2048;
    grouped_conv_fuse_kernel<<<grid, 256, 0, stream>>>(s1, s2, s3, s4, s5, w, bias, out);
}

// Round 2
// 100.152 us; speedup vs baseline: 1.0862x; 1.0862x over previous
//
#include <hip/hip_runtime.h>

// out[b,k,h,w] = w[k,0]*side5 + w[k,1]*side4 + w[k,2]*side1 + w[k,3]*side2
//              + w[k,4]*side3 + bias[k]
// B=8, K=19, H=W=512. Each thread: one float4 spatial slot of one batch,
// loops k. Singles loaded ONCE into registers -> vector-path traffic 1x.

#define KK   19
#define HW4  65536      // (512*512)/4 float4s per plane

__global__ __launch_bounds__(256) void grouped_conv_fuse_kernel(
    const float* __restrict__ s1, const float* __restrict__ s2,
    const float* __restrict__ s3, const float* __restrict__ s4,
    const float* __restrict__ s5, const float* __restrict__ w,
    const float* __restrict__ bias, float* __restrict__ out)
{
    const float4* __restrict__ v1 = (const float4*)s1;
    const float4* __restrict__ v2 = (const float4*)s2;
    const float4* __restrict__ v3 = (const float4*)s3;
    const float4* __restrict__ v4 = (const float4*)s4;
    const float4* __restrict__ v5 = (const float4*)s5;
    float4* __restrict__ vo = (float4*)out;

    // 2048 blocks: 256 blocks per batch plane (HW4/256 = 256)
    int b  = blockIdx.x >> 8;                            // 0..7
    int sp = ((blockIdx.x & 255) << 8) + threadIdx.x;    // 0..65535
    int si = (b << 16) + sp;                             // singles / per-(b,sp)

    float4 a1 = v1[si];
    float4 a2 = v2[si];
    float4 a3 = v3[si];

    long base = (long)b * KK * HW4 + sp;                 // k=0 index into 4/5/out

    #pragma unroll 4
    for (int k = 0; k < KK; ++k) {
        long i = base + (long)k * HW4;
        float4 x5 = v5[i];
        float4 x4 = v4[i];

        // wave-uniform -> scalar loads through the constant cache
        float w0 = w[k * 5 + 0];
        float w1 = w[k * 5 + 1];
        float w2 = w[k * 5 + 2];
        float w3 = w[k * 5 + 3];
        float w4 = w[k * 5 + 4];
        float bb = bias[k];

        float4 o;
        o.x = w0 * x5.x + w1 * x4.x + w2 * a1.x + w3 * a2.x + w4 * a3.x + bb;
        o.y = w0 * x5.y + w1 * x4.y + w2 * a1.y + w3 * a2.y + w4 * a3.y + bb;
        o.z = w0 * x5.z + w1 * x4.z + w2 * a1.z + w3 * a2.z + w4 * a3.z + bb;
        o.w = w0 * x5.w + w1 * x4.w + w2 * a1.w + w3 * a2.w + w4 * a3.w + bb;
        vo[i] = o;
    }
}

extern "C" void kernel_launch(void* const* d_in, const int* in_sizes, int n_in,
                              void* d_out, int out_size, void* d_ws, size_t ws_size,
                              hipStream_t stream) {
    const float* s1   = (const float*)d_in[0];
    const float* s2   = (const float*)d_in[1];
    const float* s3   = (const float*)d_in[2];
    const float* s4   = (const float*)d_in[3];
    const float* s5   = (const float*)d_in[4];
    const float* w    = (const float*)d_in[5];
    const float* bias = (const float*)d_in[6];
    float* out        = (float*)d_out;

    // 8 batches * 256 blocks/batch = 2048 blocks, one float4 per thread
    grouped_conv_fuse_kernel<<<2048, 256, 0, stream>>>(s1, s2, s3, s4, s5, w, bias, out);
}

// Round 4
// 92.919 us; speedup vs baseline: 1.1707x; 1.0778x over previous
//
#include <hip/hip_runtime.h>

// out[b,k,h,w] = w[k,0]*side5 + w[k,1]*side4 + w[k,2]*side1 + w[k,3]*side2
//              + w[k,4]*side3 + bias[k]
// B=8, K=19, H=W=512. Each thread: one float4 spatial slot of one batch,
// loops k. Singles loaded ONCE into registers; output stored NON-TEMPORAL
// (native clang vector type — HIP float4 class is rejected by the builtin)
// so the write stream doesn't evict L3-resident inputs across replays.

#define KK   19
#define HW4  65536      // (512*512)/4 float4s per plane

typedef float f32x4 __attribute__((ext_vector_type(4)));

__global__ __launch_bounds__(256) void grouped_conv_fuse_kernel(
    const float* __restrict__ s1, const float* __restrict__ s2,
    const float* __restrict__ s3, const float* __restrict__ s4,
    const float* __restrict__ s5, const float* __restrict__ w,
    const float* __restrict__ bias, float* __restrict__ out)
{
    const f32x4* __restrict__ v1 = (const f32x4*)s1;
    const f32x4* __restrict__ v2 = (const f32x4*)s2;
    const f32x4* __restrict__ v3 = (const f32x4*)s3;
    const f32x4* __restrict__ v4 = (const f32x4*)s4;
    const f32x4* __restrict__ v5 = (const f32x4*)s5;
    f32x4* __restrict__ vo = (f32x4*)out;

    // 2048 blocks: 256 blocks per batch plane (HW4/256 = 256)
    int b  = blockIdx.x >> 8;                            // 0..7
    int sp = ((blockIdx.x & 255) << 8) + threadIdx.x;    // 0..65535
    int si = (b << 16) + sp;                             // singles index

    f32x4 a1 = v1[si];
    f32x4 a2 = v2[si];
    f32x4 a3 = v3[si];

    long base = (long)b * KK * HW4 + sp;                 // k=0 index into 4/5/out

    #pragma unroll 4
    for (int k = 0; k < KK; ++k) {
        long i = base + (long)k * HW4;
        f32x4 x5 = v5[i];
        f32x4 x4 = v4[i];

        // wave-uniform -> scalar loads
        float w0 = w[k * 5 + 0];
        float w1 = w[k * 5 + 1];
        float w2 = w[k * 5 + 2];
        float w3 = w[k * 5 + 3];
        float w4 = w[k * 5 + 4];
        float bb = bias[k];

        f32x4 o = w0 * x5 + w1 * x4 + w2 * a1 + w3 * a2 + w4 * a3 + bb;

        // non-temporal: stream past L2/L3 (evict-first), keep inputs resident
        __builtin_nontemporal_store(o, &vo[i]);
    }
}

extern "C" void kernel_launch(void* const* d_in, const int* in_sizes, int n_in,
                              void* d_out, int out_size, void* d_ws, size_t ws_size,
                              hipStream_t stream) {
    const float* s1   = (const float*)d_in[0];
    const float* s2   = (const float*)d_in[1];
    const float* s3   = (const float*)d_in[2];
    const float* s4   = (const float*)d_in[3];
    const float* s5   = (const float*)d_in[4];
    const float* w    = (const float*)d_in[5];
    const float* bias = (const float*)d_in[6];
    float* out        = (float*)d_out;

    grouped_conv_fuse_kernel<<<2048, 256, 0, stream>>>(s1, s2, s3, s4, s5, w, bias, out);
}

// Round 5
// 78.590 us; speedup vs baseline: 1.3842x; 1.1823x over previous
//
#include <hip/hip_runtime.h>

// out[b,k,h,w] = w[k,0]*side5 + w[k,1]*side4 + w[k,2]*side1 + w[k,3]*side2
//              + w[k,4]*side3 + bias[k]
// B=8, K=19, H=W=512.
// L3 residency plan (L3 = 256 MiB, inputs = 328 MiB):
//   resident: singles (24 MiB) + side4/5 for k<14 (224 MiB) = 248 MiB
//   streamed (non-temporal loads): side4/5 for k>=14 (80 MiB)
//   output: non-temporal stores (never re-read; don't evict inputs)
// Each thread owns TWO float4 spatial slots -> 4 loads in flight per k-iter.

#define KK   19
#define HW4  65536      // (512*512)/4 float4s per plane
#define KRES 14         // k < KRES uses normal (caching) loads

typedef float f32x4 __attribute__((ext_vector_type(4)));

__global__ __launch_bounds__(256) void grouped_conv_fuse_kernel(
    const float* __restrict__ s1, const float* __restrict__ s2,
    const float* __restrict__ s3, const float* __restrict__ s4,
    const float* __restrict__ s5, const float* __restrict__ w,
    const float* __restrict__ bias, float* __restrict__ out)
{
    const f32x4* __restrict__ v1 = (const f32x4*)s1;
    const f32x4* __restrict__ v2 = (const f32x4*)s2;
    const f32x4* __restrict__ v3 = (const f32x4*)s3;
    const f32x4* __restrict__ v4 = (const f32x4*)s4;
    const f32x4* __restrict__ v5 = (const f32x4*)s5;
    f32x4* __restrict__ vo = (f32x4*)out;

    // 1024 blocks: 128 blocks per batch, each block covers 512 float4 slots
    int b   = blockIdx.x >> 7;                            // 0..7
    int sp0 = ((blockIdx.x & 127) << 9) + threadIdx.x;    // first slot
    int sp1 = sp0 + 256;                                  // second slot
    int si0 = (b << 16) + sp0;
    int si1 = si0 + 256;

    f32x4 p1 = v1[si0], q1 = v1[si1];
    f32x4 p2 = v2[si0], q2 = v2[si1];
    f32x4 p3 = v3[si0], q3 = v3[si1];

    long base0 = (long)b * KK * HW4 + sp0;
    long base1 = base0 + 256;

    // ---- resident ks: normal loads (allocate in L2/L3) ----
    #pragma unroll 2
    for (int k = 0; k < KRES; ++k) {
        long i0 = base0 + (long)k * HW4;
        long i1 = base1 + (long)k * HW4;
        f32x4 x5a = v5[i0], x5b = v5[i1];
        f32x4 x4a = v4[i0], x4b = v4[i1];

        float w0 = w[k * 5 + 0], w1 = w[k * 5 + 1], w2 = w[k * 5 + 2];
        float w3 = w[k * 5 + 3], w4 = w[k * 5 + 4], bb = bias[k];

        f32x4 oa = w0 * x5a + w1 * x4a + w2 * p1 + w3 * p2 + w4 * p3 + bb;
        f32x4 ob = w0 * x5b + w1 * x4b + w2 * q1 + w3 * q2 + w4 * q3 + bb;
        __builtin_nontemporal_store(oa, &vo[i0]);
        __builtin_nontemporal_store(ob, &vo[i1]);
    }

    // ---- streamed ks: non-temporal loads (don't evict the resident set) ----
    #pragma unroll 2
    for (int k = KRES; k < KK; ++k) {
        long i0 = base0 + (long)k * HW4;
        long i1 = base1 + (long)k * HW4;
        f32x4 x5a = __builtin_nontemporal_load(&v5[i0]);
        f32x4 x5b = __builtin_nontemporal_load(&v5[i1]);
        f32x4 x4a = __builtin_nontemporal_load(&v4[i0]);
        f32x4 x4b = __builtin_nontemporal_load(&v4[i1]);

        float w0 = w[k * 5 + 0], w1 = w[k * 5 + 1], w2 = w[k * 5 + 2];
        float w3 = w[k * 5 + 3], w4 = w[k * 5 + 4], bb = bias[k];

        f32x4 oa = w0 * x5a + w1 * x4a + w2 * p1 + w3 * p2 + w4 * p3 + bb;
        f32x4 ob = w0 * x5b + w1 * x4b + w2 * q1 + w3 * q2 + w4 * q3 + bb;
        __builtin_nontemporal_store(oa, &vo[i0]);
        __builtin_nontemporal_store(ob, &vo[i1]);
    }
}

extern "C" void kernel_launch(void* const* d_in, const int* in_sizes, int n_in,
                              void* d_out, int out_size, void* d_ws, size_t ws_size,
                              hipStream_t stream) {
    const float* s1   = (const float*)d_in[0];
    const float* s2   = (const float*)d_in[1];
    const float* s3   = (const float*)d_in[2];
    const float* s4   = (const float*)d_in[3];
    const float* s5   = (const float*)d_in[4];
    const float* w    = (const float*)d_in[5];
    const float* bias = (const float*)d_in[6];
    float* out        = (float*)d_out;

    grouped_conv_fuse_kernel<<<1024, 256, 0, stream>>>(s1, s2, s3, s4, s5, w, bias, out);
}